// Round 12
// baseline (1034.221 us; speedup 1.0000x reference)
//
#include <hip/hip_runtime.h>
#include <math.h>

#define NTY 5
#define NET 10
#define NTOT 307000
#define ETOT 6800000
#define GDIM 1024
#define PDIM 768
#define NGEMMB 7335
#define GSH 2445                      /* gemm share per mega kernel (3 shares) */
#define NBINB 1668                    /* 4096 edges/block */
#define NBK 2949                      /* total buckets */
#define NMEGA_C (NBINB + GSH)
#define NMEGA_B (NBINB + GSH)
#define NMEGA_S (NBK + GSH)
#define NPREPB 802                    /* 2 prep + 640 Wt0 + 160 Wt1 */

using short8 = __attribute__((ext_vector_type(8))) short;
using f32x4  = __attribute__((ext_vector_type(4))) float;

// ---- compile-time problem tables (host) ----
static const int kSRCT[NET]= {0,0,0,4,4,1,2,3,1,2};
static const int kNT[NTY]  = {5000,50000,100000,150000,2000};
static const int kTOFF[NTY]= {0,5000,55000,155000,305000};
static const int kRB[NET+1]= {0,50000,150000,300000,350000,450000,455000,460000,465000,467000,469000};

// ---- device tables ----
__device__ const int gOB[NET]   = {0,50001,150002,300003,350004,450005,455006,460007,465008,467009};
__device__ const int gEB[NET+1] = {0,500000,1500000,2500000,2800000,3400000,3900000,4900000,5900000,6200000,6800000};
__device__ const int gSB[NET]   = {0,5000,10000,15000,17000,19000,69000,169000,319000,369000};
__device__ const int gRB[NET]   = {0,50000,150000,300000,350000,450000,455000,460000,465000,467000};
__device__ const int gND[NET]   = {50000,100000,150000,50000,100000,5000,5000,5000,2000,2000};
__device__ const int gTOFF[NTY] = {0,5000,55000,155000,305000};
__device__ const int gNIN[NTY]  = {3,2,2,1,2};
__device__ const int gINET[NTY][3] = {{5,6,7},{0,3,0},{1,4,0},{2,0,0},{8,9,0}};
__device__ const int gNJ[NET]   = {3,0,0,2,0,2,2,1,0,0};
__device__ const int gTG[NET][3]= {{5,6,7},{0,0,0},{0,0,0},{8,9,0},{0,0,0},{0,3,0},{1,4,0},{2,0,0},{0,0,0},{0,0,0}};
__device__ const int gDSTT[NET] = {1,2,3,1,2,0,0,0,4,4};
// bucket tables: shift per et, bucket base per et
__device__ const int gSH[NET]   = {8,8,8,8,8,4,4,4,4,4};
__device__ const int gBKB[NET+1]= {0,196,587,1173,1369,1760,2073,2386,2699,2824,2949};
// bin blocks per et (4096 edges each), cumulative
__device__ const int gBC[NET+1] = {0,123,368,613,687,834,957,1202,1447,1521,1668};

__device__ __forceinline__ unsigned short f2bf(float f){
  unsigned int u = __float_as_uint(f);
  u += 0x7fffu + ((u>>16)&1u);
  return (unsigned short)(u>>16);
}
__device__ __forceinline__ float bf2f(unsigned short h){
  return __uint_as_float(((unsigned int)h)<<16);
}

struct PrepTab {
  const float* Wd0; const float* ad0; const float* b0;
  const float* Wd1; const float* ad1; const float* b1;
  const float* Ws0; const float* Ws1;
  float* wv0; float* wv1; float* bs0; float* bs1;
  unsigned short* Wt0; unsigned short* Wt1;
};
struct PoolTab { const int* batch[NTY]; const float* x[NTY]; int nt[NTY]; };
struct GemmArgs {
  const float* X[NET];
  const unsigned short* Wt;      // [et][col(64)][K] bf16
  const float* asrc;
  const float* wv;
  unsigned short* hs;            // bf16
  float* ssrc;
  float* sdst;
  int K;
};
struct MCTab {
  GemmArgs g;
  const int* ei[NET];
  int* cntB;
};
struct MBTab {
  GemmArgs g;
  const int* ei[NET];
  int* gcur;
  int2* pairs;
};
struct MSTab {
  GemmArgs g;
  const int2* pairs;
  const int* cntB;
  const int* segB;
  const int* exB;
  int* offs;
  int* csr;
};
struct AggTab {
  const int* offs;
  const int* csr;
  const unsigned short* hs;      // bf16
  const float* ssrc;
  const float* sdst;
  const float* bsum;
  float* xout;
};

// ---------------- weight prep + W transposes ----------------
__global__ __launch_bounds__(256) void k_prep(PrepTab p) {
  int b = blockIdx.x;
  int tid = threadIdx.x;
  if (b == 0) {
    for (int e2=0; e2<NET; e2++){
      const float* W = p.Wd0 + (long)e2*256*64;
      const float* a = p.ad0 + e2*64;
      float s=0.f;
      #pragma unroll 8
      for (int c=0;c<64;c++) s += W[tid*64+c]*a[c];
      p.wv0[e2*256+tid]=s;
    }
    for (int idx=tid; idx<320; idx+=256){
      int ty=idx>>6, c=idx&63; float s=0.f;
      #pragma unroll
      for (int i=0;i<NET;i++) if (gDSTT[i]==ty) s += p.b0[i*64+c];
      p.bs0[idx]=s;
    }
    return;
  }
  if (b == 1) {
    if (tid < 64){
      for (int e2=0; e2<NET; e2++){
        const float* W = p.Wd1 + (long)e2*64*64;
        const float* a = p.ad1 + e2*64;
        float s=0.f;
        #pragma unroll 8
        for (int c=0;c<64;c++) s += W[tid*64+c]*a[c];
        p.wv1[e2*256+tid]=s;
      }
    }
    for (int idx=tid; idx<320; idx+=256){
      int ty=idx>>6, c=idx&63; float s=0.f;
      #pragma unroll
      for (int i=0;i<NET;i++) if (gDSTT[i]==ty) s += p.b1[i*64+c];
      p.bs1[idx]=s;
    }
    return;
  }
  if (b < 2+640) {            // layer0 W transpose: Wt0[et][col][256]
    int i = b-2;
    int et = i>>6, chunk = i&63;
    int idx = chunk*256 + tid;          // col*256 + k
    int col = idx>>8, k = idx&255;
    p.Wt0[(long)et*16384 + idx] = f2bf(p.Ws0[(long)et*16384 + k*64 + col]);
    return;
  }
  {                           // layer1 W transpose: Wt1[et][col][64]
    int i = b-642;
    int et = i>>4, chunk = i&15;
    int idx = chunk*256 + tid;          // col*64 + k
    int col = idx>>6, k = idx&63;
    p.Wt1[(long)et*4096 + idx] = f2bf(p.Ws1[(long)et*4096 + k*64 + col]);
  }
}

// ---------------- bucket scan: exact csr bases + padded pair segments ----------------
__global__ __launch_bounds__(256) void k_scanB(const int* __restrict__ cntB,
                                               int* __restrict__ segB,
                                               int* __restrict__ gcurB,
                                               int* __restrict__ exB) {
  __shared__ int tp[256], te[256];
  int tid = threadIdx.x;
  int base = tid*12;
  int locP[12], locE[12];
  int sp=0, se=0;
  #pragma unroll
  for (int i=0;i<12;i++){
    int b = base+i;
    int v = (b<NBK) ? cntB[b] : 0;
    locE[i]=se; se += v;
    locP[i]=sp; sp += (v+7)&~7;
  }
  tp[tid]=sp; te[tid]=se; __syncthreads();
  for (int off=1; off<256; off<<=1){
    int xp = (tid>=off)? tp[tid-off] : 0;
    int xe = (tid>=off)? te[tid-off] : 0;
    __syncthreads();
    tp[tid]+=xp; te[tid]+=xe;
    __syncthreads();
  }
  int preP = tp[tid]-sp, preE = te[tid]-se;
  #pragma unroll
  for (int i=0;i<12;i++){
    int b = base+i;
    if (b<NBK){
      int v = preP + locP[i];
      segB[b]=v; gcurB[b]=v;
      exB[b]=preE + locE[i];
    }
  }
}

// ---------------- MFMA gemm body: LDS-free, barrier-free ----------------
__device__ __forceinline__ void gemm_block(const GemmArgs& t, int b) {
  const int GB1=79,GB2=158,GB3=237,GB4=269,GB5=301,GB6=1083,GB7=2646,GB8=4990,GB9=5772;
  int et = (b>=GB1)+(b>=GB2)+(b>=GB3)+(b>=GB4)+(b>=GB5)+(b>=GB6)+(b>=GB7)+(b>=GB8)+(b>=GB9);
  const int GBb[NET] = {0,GB1,GB2,GB3,GB4,GB5,GB6,GB7,GB8,GB9};
  const int NSa[NET] = {5000,5000,5000,2000,2000,50000,100000,150000,50000,100000};
  int lb = b - GBb[et];
  int Ns = NSa[et];
  int K = t.K;
  const float* X = t.X[et];
  const unsigned short* Wt = t.Wt + (long)et*64*K;
  const float* avec = t.asrc + et*64;
  int sbase = gSB[et];
  unsigned short* HS = t.hs + (long)sbase*64;
  float* score = t.ssrc + sbase;

  int nj = gNJ[et];
  const float* wvA = t.wv + gTG[et][0]*256;
  const float* wvB = t.wv + gTG[et][1]*256;
  const float* wvC = t.wv + gTG[et][2]*256;

  int tid = threadIdx.x;
  int w = tid>>6, lane = tid&63;
  int row0 = lb*64;
  int l15 = lane&15, lg = lane>>4;
  int arow = row0 + w*16 + l15;          // A row this lane loads
  bool rok = arow < Ns;
  const float* xrow = X + (long)(rok ? arow : 0)*K;
  const unsigned short* wtc0 = Wt + (long)( 0+l15)*K;
  const unsigned short* wtc1 = Wt + (long)(16+l15)*K;
  const unsigned short* wtc2 = Wt + (long)(32+l15)*K;
  const unsigned short* wtc3 = Wt + (long)(48+l15)*K;
  int kb = lg*8;

  f32x4 acc0={0.f,0.f,0.f,0.f}, acc1={0.f,0.f,0.f,0.f}, acc2={0.f,0.f,0.f,0.f}, acc3={0.f,0.f,0.f,0.f};
  float asd0=0.f, asd1=0.f, asd2=0.f;

  for (int k0=0; k0<K; k0+=32){
    float4 xa = make_float4(0.f,0.f,0.f,0.f), xb = make_float4(0.f,0.f,0.f,0.f);
    if (rok) {
      xa = *(const float4*)(xrow + k0 + kb);
      xb = *(const float4*)(xrow + k0 + kb + 4);
    }
    short8 af;
    af[0]=(short)f2bf(xa.x); af[1]=(short)f2bf(xa.y);
    af[2]=(short)f2bf(xa.z); af[3]=(short)f2bf(xa.w);
    af[4]=(short)f2bf(xb.x); af[5]=(short)f2bf(xb.y);
    af[6]=(short)f2bf(xb.z); af[7]=(short)f2bf(xb.w);
    short8 b0 = *(const short8*)(wtc0 + k0 + kb);
    short8 b1 = *(const short8*)(wtc1 + k0 + kb);
    short8 b2 = *(const short8*)(wtc2 + k0 + kb);
    short8 b3 = *(const short8*)(wtc3 + k0 + kb);
    acc0 = __builtin_amdgcn_mfma_f32_16x16x32_bf16(af, b0, acc0, 0, 0, 0);
    acc1 = __builtin_amdgcn_mfma_f32_16x16x32_bf16(af, b1, acc1, 0, 0, 0);
    acc2 = __builtin_amdgcn_mfma_f32_16x16x32_bf16(af, b2, acc2, 0, 0, 0);
    acc3 = __builtin_amdgcn_mfma_f32_16x16x32_bf16(af, b3, acc3, 0, 0, 0);
    if (nj) {
      asd0 += xa.x*wvA[k0+kb+0] + xa.y*wvA[k0+kb+1] + xa.z*wvA[k0+kb+2] + xa.w*wvA[k0+kb+3]
            + xb.x*wvA[k0+kb+4] + xb.y*wvA[k0+kb+5] + xb.z*wvA[k0+kb+6] + xb.w*wvA[k0+kb+7];
      if (nj > 1)
        asd1 += xa.x*wvB[k0+kb+0] + xa.y*wvB[k0+kb+1] + xa.z*wvB[k0+kb+2] + xa.w*wvB[k0+kb+3]
              + xb.x*wvB[k0+kb+4] + xb.y*wvB[k0+kb+5] + xb.z*wvB[k0+kb+6] + xb.w*wvB[k0+kb+7];
      if (nj > 2)
        asd2 += xa.x*wvC[k0+kb+0] + xa.y*wvC[k0+kb+1] + xa.z*wvC[k0+kb+2] + xa.w*wvC[k0+kb+3]
              + xb.x*wvC[k0+kb+4] + xb.y*wvC[k0+kb+5] + xb.z*wvC[k0+kb+6] + xb.w*wvC[k0+kb+7];
    }
  }

  if (nj) {
    // reduce over lg groups (lanes l15, l15+16, l15+32, l15+48)
    asd0 += __shfl_xor(asd0, 16); asd0 += __shfl_xor(asd0, 32);
    asd1 += __shfl_xor(asd1, 16); asd1 += __shfl_xor(asd1, 32);
    asd2 += __shfl_xor(asd2, 16); asd2 += __shfl_xor(asd2, 32);
    if (lg == 0 && rok) {
      t.sdst[gRB[gTG[et][0]] + arow] = asd0;
      if (nj > 1) t.sdst[gRB[gTG[et][1]] + arow] = asd1;
      if (nj > 2) t.sdst[gRB[gTG[et][2]] + arow] = asd2;
    }
  }

  // epilogue: C/D layout col=lane&15, row=(lane>>4)*4+reg  [guide-verified]
  float av0 = avec[ 0+l15], av1 = avec[16+l15], av2 = avec[32+l15], av3 = avec[48+l15];
  int growb = row0 + w*16 + lg*4;
  #pragma unroll
  for (int r=0;r<4;r++){
    int grow = growb + r;
    if (grow < Ns){
      HS[(long)grow*64 +  0+l15] = f2bf(acc0[r]);
      HS[(long)grow*64 + 16+l15] = f2bf(acc1[r]);
      HS[(long)grow*64 + 32+l15] = f2bf(acc2[r]);
      HS[(long)grow*64 + 48+l15] = f2bf(acc3[r]);
    }
    float s = acc0[r]*av0 + acc1[r]*av1 + acc2[r]*av2 + acc3[r]*av3;
    s += __shfl_xor(s, 1);
    s += __shfl_xor(s, 2);
    s += __shfl_xor(s, 4);
    s += __shfl_xor(s, 8);
    if (l15==0 && grow<Ns) score[grow]=s;
  }
}

__global__ __launch_bounds__(256) void k_gemm_all(GemmArgs t) {
  gemm_block(t, blockIdx.x);
}

// ---------------- megaCount: LDS bucket histogram + gemm0[0:GSH] ----------------
__global__ __launch_bounds__(256) void k_megaCount(MCTab t) {
  __shared__ int cnt[640];
  long long b = blockIdx.x;
  const long long G = GSH, T = NMEGA_C;
  long long lo = (b*G)/T, hi = ((b+1)*G)/T;
  if (hi > lo) {
    gemm_block(t.g, (int)lo);
    return;
  }
  int sidx = (int)(b - lo);          // 0..NBINB-1
  int et=0;
  #pragma unroll
  for (int i=0;i<NET;i++) if (sidx >= gBC[i+1]) et=i+1;
  int lb = sidx - gBC[et];
  int E = gEB[et+1]-gEB[et];
  int e0 = lb*4096;
  int eend = e0+4096; if (eend > E) eend = E;
  int sh = gSH[et];
  int nbk = gBKB[et+1]-gBKB[et];
  const int* D = t.ei[et] + E;
  int tid = threadIdx.x;
  for (int j=tid; j<nbk; j+=256) cnt[j]=0;
  __syncthreads();
  #pragma unroll
  for (int i=0;i<16;i++){
    int idx = e0 + i*256 + tid;
    if (idx < eend) atomicAdd(&cnt[D[idx]>>sh], 1);
  }
  __syncthreads();
  int* cb = t.cntB + gBKB[et];
  for (int j=tid; j<nbk; j+=256) if (cnt[j]) atomicAdd(&cb[j], cnt[j]);
}

// ---------------- megaBin: bin pairs into bucket segments + gemm0[GSH:2*GSH] ----------------
__global__ __launch_bounds__(256) void k_megaBin(MBTab t) {
  __shared__ int cnt[640], cnt2[640], gb2[640];
  long long b = blockIdx.x;
  const long long G = GSH, T = NMEGA_B;
  long long lo = (b*G)/T, hi = ((b+1)*G)/T;
  if (hi > lo) {
    gemm_block(t.g, GSH + (int)lo);
    return;
  }
  int sidx = (int)(b - lo);          // 0..NBINB-1
  int et=0;
  #pragma unroll
  for (int i=0;i<NET;i++) if (sidx >= gBC[i+1]) et=i+1;
  int lb = sidx - gBC[et];
  int E = gEB[et+1]-gEB[et];
  int e0 = lb*4096;
  int eend = e0+4096; if (eend > E) eend = E;
  int sh = gSH[et];
  int nbk = gBKB[et+1]-gBKB[et];
  int bkb = gBKB[et];
  const int* EI = t.ei[et];
  int tid = threadIdx.x;
  int sr[16], dv[16];
  #pragma unroll
  for (int i=0;i<16;i++){
    int idx = e0 + i*256 + tid;
    if (idx < eend){ sr[i]=EI[idx]; dv[i]=EI[E+idx]; } else dv[i] = -1;
  }
  for (int j=tid; j<nbk; j+=256){ cnt[j]=0; cnt2[j]=0; }
  __syncthreads();
  #pragma unroll
  for (int i=0;i<16;i++) if (dv[i]>=0) atomicAdd(&cnt[dv[i]>>sh], 1);
  __syncthreads();
  for (int j=tid; j<nbk; j+=256) if (cnt[j]) gb2[j] = atomicAdd(&t.gcur[bkb+j], cnt[j]);
  __syncthreads();
  #pragma unroll
  for (int i=0;i<16;i++) if (dv[i]>=0){
    int bb = dv[i]>>sh;
    int p = gb2[bb] + atomicAdd(&cnt2[bb], 1);
    t.pairs[p] = make_int2(sr[i], dv[i]);
  }
}

// ---------------- megaScat: bucket-local LDS-exact scatter + offs + gemm0[2*GSH:] ----------------
__global__ __launch_bounds__(256) void k_megaScat(MSTab t) {
  __shared__ int cnt[256], sd[256], lcur[256];
  long long b = blockIdx.x;
  const long long G = GSH, T = NMEGA_S;
  long long lo = (b*G)/T, hi = ((b+1)*G)/T;
  if (hi > lo) {
    gemm_block(t.g, 2*GSH + (int)lo);
    return;
  }
  int b2 = (int)(b - lo);            // bucket id 0..NBK-1
  int et=0;
  #pragma unroll
  for (int i=0;i<NET;i++) if (b2 >= gBKB[i+1]) et=i+1;
  int lb = b2 - gBKB[et];
  int sh = gSH[et];
  int nd = gND[et];
  int d0 = lb<<sh;
  int ndst = (1<<sh); if (d0+ndst > nd) ndst = nd-d0;
  int n = t.cntB[b2];
  const int2* pr = t.pairs + t.segB[b2];
  int csrBase = t.exB[b2] - gEB[et];
  int tid = threadIdx.x;
  cnt[tid]=0;
  __syncthreads();
  for (int i=tid; i<n; i+=256) atomicAdd(&cnt[pr[i].y - d0], 1);
  __syncthreads();
  int v = (tid<ndst)? cnt[tid] : 0;
  sd[tid]=v; __syncthreads();
  for (int off=1; off<256; off<<=1){
    int x = (tid>=off)? sd[tid-off] : 0;
    __syncthreads();
    sd[tid]+=x;
    __syncthreads();
  }
  int excl = sd[tid]-v;
  lcur[tid] = excl;
  if (tid < ndst) t.offs[gOB[et] + d0 + tid] = csrBase + excl;
  if (tid==0 && b2 == gBKB[et+1]-1) t.offs[gOB[et] + nd] = gEB[et+1]-gEB[et];
  __syncthreads();
  int* csrb = t.csr + gEB[et] + csrBase;
  for (int i=tid; i<n; i+=256){
    int2 p = pr[i];
    int pos = atomicAdd(&lcur[p.y - d0], 1);
    csrb[pos] = p.x;
  }
}

// ---------------- fused aggregation: wave-cooperative edges, readlane broadcast ----------------
__global__ __launch_bounds__(256) void k_agg_all(AggTab t) {
  int nb = blockIdx.x;
  int node0;
  if (nb < 1250)      node0 = nb*4;                       // tag (heavy) first
  else if (nb < 1750) node0 = 305000 + (nb-1250)*4;       // module (heavy)
  else                node0 = 5000 + (nb-1750)*4;         // q/a/c (light)
  int node = node0 + (threadIdx.x>>6);
  int lane = threadIdx.x & 63;
  int ty = (node>=5000)+(node>=55000)+(node>=155000)+(node>=305000);
  int r = node - gTOFF[ty];
  float outacc = 0.f;
  int ne = gNIN[ty];
  for (int ii=0; ii<ne; ii++) {
    int et = gINET[ty][ii];
    float sd = t.sdst[gRB[et] + r];
    int ob = gOB[et];
    int beg = t.offs[ob + r];
    int end = t.offs[ob + r + 1];
    if (beg >= end) continue;
    const int* cs = t.csr + gEB[et];
    const float* ss = t.ssrc + gSB[et];
    const unsigned short* hsb = t.hs + (long)gSB[et]*64;
    float denl = 0.f, acc = 0.f;
    for (int chunk = beg; chunk < end; chunk += 64) {
      int n = end - chunk; if (n > 64) n = 64;
      int s = 0; float ex = 0.f;
      if (lane < n) {
        s = cs[chunk + lane];
        float l = ss[s] + sd;
        l = (l>0.f)? l : 0.2f*l;
        ex = __expf(l);
      }
      denl += ex;
      unsigned int exu = __float_as_uint(ex);
      int j = 0;
      for (; j+8 <= n; j += 8) {
        int a0=__builtin_amdgcn_readlane(s,j+0), a1=__builtin_amdgcn_readlane(s,j+1);
        int a2=__builtin_amdgcn_readlane(s,j+2), a3=__builtin_amdgcn_readlane(s,j+3);
        int a4=__builtin_amdgcn_readlane(s,j+4), a5=__builtin_amdgcn_readlane(s,j+5);
        int a6=__builtin_amdgcn_readlane(s,j+6), a7=__builtin_amdgcn_readlane(s,j+7);
        float e0=__uint_as_float(__builtin_amdgcn_readlane(exu,j+0));
        float e1=__uint_as_float(__builtin_amdgcn_readlane(exu,j+1));
        float e2=__uint_as_float(__builtin_amdgcn_readlane(exu,j+2));
        float e3=__uint_as_float(__builtin_amdgcn_readlane(exu,j+3));
        float e4=__uint_as_float(__builtin_amdgcn_readlane(exu,j+4));
        float e5=__uint_as_float(__builtin_amdgcn_readlane(exu,j+5));
        float e6=__uint_as_float(__builtin_amdgcn_readlane(exu,j+6));
        float e7=__uint_as_float(__builtin_amdgcn_readlane(exu,j+7));
        float h0=bf2f(hsb[(long)a0*64+lane]);
        float h1=bf2f(hsb[(long)a1*64+lane]);
        float h2=bf2f(hsb[(long)a2*64+lane]);
        float h3=bf2f(hsb[(long)a3*64+lane]);
        float h4=bf2f(hsb[(long)a4*64+lane]);
        float h5=bf2f(hsb[(long)a5*64+lane]);
        float h6=bf2f(hsb[(long)a6*64+lane]);
        float h7=bf2f(hsb[(long)a7*64+lane]);
        acc += e0*h0 + e1*h1 + e2*h2 + e3*h3;
        acc += e4*h4 + e5*h5 + e6*h6 + e7*h7;
      }
      for (; j<n; j++) {
        int aj=__builtin_amdgcn_readlane(s,j);
        float ej=__uint_as_float(__builtin_amdgcn_readlane(exu,j));
        acc += ej * bf2f(hsb[(long)aj*64+lane]);
      }
    }
    #pragma unroll
    for (int off=32; off; off>>=1) denl += __shfl_xor(denl, off);
    outacc += acc/(denl+1e-16f);
  }
  float o = outacc + t.bsum[ty*64+lane];
  t.xout[(long)node*64+lane] = fmaxf(o,0.f);
}

// ---------------- pooling + head ----------------
__global__ __launch_bounds__(64) void k_pool(PoolTab t, float* __restrict__ pooled) {
  int g = blockIdx.x; int ty = blockIdx.y; int lane = threadIdx.x;
  const int* batch = t.batch[ty];
  int n = t.nt[ty];
  int lo=0, hi=0;
  if (lane==0){
    int a=0,b2=n;
    while(a<b2){int mm=(a+b2)>>1; if (batch[mm]<g) a=mm+1; else b2=mm;}
    lo=a;
    a=lo; b2=n;
    while(a<b2){int mm=(a+b2)>>1; if (batch[mm]<g+1) a=mm+1; else b2=mm;}
    hi=a;
  }
  lo=__shfl(lo,0); hi=__shfl(hi,0);
  const float* x = t.x[ty];
  float acc=0.f;
  for (int i=lo;i<hi;i++) acc += x[(long)i*64+lane];
  int cnt = hi-lo;
  pooled[(long)g*320 + ty*64 + lane] = acc / (float)(cnt>0?cnt:1);
}

__global__ __launch_bounds__(256) void k_final(
    const float* __restrict__ pooled, const float* __restrict__ post,
    const float* __restrict__ Wlin, const float* __restrict__ blin,
    float* __restrict__ out)
{
  int w = (blockIdx.x*256+threadIdx.x)>>6;
  int lane = threadIdx.x&63;
  if (w>=GDIM) return;
  float a0=0.f,a1=0.f;
  for (int k=lane;k<320+PDIM;k+=64){
    float v = (k<320) ? pooled[(long)w*320+k] : post[(long)w*PDIM + (k-320)];
    a0 += v*Wlin[k*2];
    a1 += v*Wlin[k*2+1];
  }
  #pragma unroll
  for (int off=32;off;off>>=1){ a0+=__shfl_xor(a0,off); a1+=__shfl_xor(a1,off); }
  if (lane==0){
    float z0=a0+blin[0], z1=a1+blin[1];
    z0=fmaxf(z0,0.f); z1=fmaxf(z1,0.f);
    float mm=fmaxf(z0,z1);
    float e0=__expf(z0-mm), e1=__expf(z1-mm);
    float inv = 1.f/(e0+e1);
    out[w*2+0]=e0*inv; out[w*2+1]=e1*inv;
  }
}

extern "C" void kernel_launch(void* const* d_in, const int* in_sizes, int n_in,
                              void* d_out, int out_size, void* d_ws, size_t ws_size,
                              hipStream_t stream) {
  (void)in_sizes; (void)n_in; (void)out_size; (void)ws_size;
  char* ws = (char*)d_ws;
  size_t off = 0;
  auto A = [&](size_t nbytes){ size_t o=off; off=(off+nbytes+255)&~((size_t)255); return o; };
  size_t xbuf1_o = A((size_t)NTOT*64*4);
  size_t xbuf2_o = A((size_t)NTOT*64*4);
  size_t hs_o    = A((size_t)469000*64*2);
  size_t csr_o   = A((size_t)ETOT*4);
  size_t pairs_o = A((size_t)6832000*8);
  size_t offs_o  = A((size_t)469010*4);
  size_t ssrc_o  = A((size_t)469000*4);
  size_t sdst_o  = A((size_t)469000*4);
  size_t pool_o  = A((size_t)GDIM*320*4);
  size_t wv0_o   = A((size_t)NET*256*4);
  size_t wv1_o   = A((size_t)NET*256*4);
  size_t bs0_o   = A((size_t)320*4);
  size_t bs1_o   = A((size_t)320*4);
  size_t cntB_o  = A((size_t)NBK*4);
  size_t segB_o  = A((size_t)NBK*4);
  size_t gcurB_o = A((size_t)NBK*4);
  size_t exB_o   = A((size_t)NBK*4);
  size_t wt0_o   = A((size_t)NET*64*256*2);
  size_t wt1_o   = A((size_t)NET*64*64*2);

  float* xbuf1 = (float*)(ws + xbuf1_o);
  float* xbuf2 = (float*)(ws + xbuf2_o);
  unsigned short* hsB = (unsigned short*)(ws + hs_o);
  int*   csr   = (int*)(ws + csr_o);
  int2*  pairs = (int2*)(ws + pairs_o);
  int*   offs  = (int*)(ws + offs_o);
  float* ssrcB = (float*)(ws + ssrc_o);
  float* sdstA = (float*)(ws + sdst_o);
  float* pooled= (float*)(ws + pool_o);
  float* wv0   = (float*)(ws + wv0_o);
  float* wv1   = (float*)(ws + wv1_o);
  float* bs0   = (float*)(ws + bs0_o);
  float* bs1   = (float*)(ws + bs1_o);
  int*   cntB  = (int*)(ws + cntB_o);
  int*   segB  = (int*)(ws + segB_o);
  int*   gcurB = (int*)(ws + gcurB_o);
  int*   exB   = (int*)(ws + exB_o);
  unsigned short* Wt0 = (unsigned short*)(ws + wt0_o);
  unsigned short* Wt1 = (unsigned short*)(ws + wt1_o);

  PrepTab pp;
  pp.Wd0 = (const float*)d_in[22]; pp.ad0 = (const float*)d_in[24]; pp.b0 = (const float*)d_in[25];
  pp.Wd1 = (const float*)d_in[27]; pp.ad1 = (const float*)d_in[29]; pp.b1 = (const float*)d_in[30];
  pp.Ws0 = (const float*)d_in[21]; pp.Ws1 = (const float*)d_in[26];
  pp.wv0 = wv0; pp.wv1 = wv1; pp.bs0 = bs0; pp.bs1 = bs1;
  pp.Wt0 = Wt0; pp.Wt1 = Wt1;

  hipMemsetAsync(cntB, 0, (size_t)NBK*4, stream);
  k_prep<<<NPREPB,256,0,stream>>>(pp);

  // ---- megaCount: bucket histogram + first share of layer-0 gemm ----
  MCTab mc;
  for (int e=0;e<NET;e++) mc.g.X[e] = (const float*)d_in[kSRCT[e]];
  mc.g.Wt = Wt0;
  mc.g.asrc = (const float*)d_in[23];
  mc.g.wv = wv0; mc.g.hs = hsB; mc.g.ssrc = ssrcB; mc.g.sdst = sdstA; mc.g.K = 256;
  for (int i=0;i<NET;i++) mc.ei[i] = (const int*)d_in[6+i];
  mc.cntB = cntB;
  k_megaCount<<<NMEGA_C,256,0,stream>>>(mc);

  k_scanB<<<1,256,0,stream>>>(cntB, segB, gcurB, exB);

  // ---- megaBin: pair binning + second share of gemm0 ----
  MBTab mb;
  mb.g = mc.g;
  for (int i=0;i<NET;i++) mb.ei[i] = (const int*)d_in[6+i];
  mb.gcur = gcurB; mb.pairs = pairs;
  k_megaBin<<<NMEGA_B,256,0,stream>>>(mb);

  // ---- megaScat: bucket-local scatter + offs + last share of gemm0 ----
  MSTab ms;
  ms.g = mc.g;
  ms.pairs = pairs; ms.cntB = cntB; ms.segB = segB; ms.exB = exB;
  ms.offs = offs; ms.csr = csr;
  k_megaScat<<<NMEGA_S,256,0,stream>>>(ms);

  // ---- layer-0 agg ----
  AggTab a0;
  a0.offs = offs; a0.csr = csr; a0.hs = hsB; a0.ssrc = ssrcB;
  a0.sdst = sdstA; a0.bsum = bs0; a0.xout = xbuf1;
  k_agg_all<<<NTOT/4,256,0,stream>>>(a0);

  // ---- layer-1 gemm ----
  GemmArgs g1;
  for (int e=0;e<NET;e++) g1.X[e] = (const float*)(xbuf1 + (long)kTOFF[kSRCT[e]]*64);
  g1.Wt = Wt1;
  g1.asrc = (const float*)d_in[28];
  g1.wv = wv1; g1.hs = hsB; g1.ssrc = ssrcB; g1.sdst = sdstA; g1.K = 64;
  k_gemm_all<<<NGEMMB,256,0,stream>>>(g1);

  // ---- layer-1 agg ----
  AggTab a1;
  a1.offs = offs; a1.csr = csr; a1.hs = hsB; a1.ssrc = ssrcB;
  a1.sdst = sdstA; a1.bsum = bs1; a1.xout = xbuf2;
  k_agg_all<<<NTOT/4,256,0,stream>>>(a1);

  // ---- pooling + head ----
  PoolTab pt;
  for (int t=0;t<NTY;t++){
    pt.batch[t] = (const int*)d_in[16+t];
    pt.x[t] = (const float*)(xbuf2 + (long)kTOFF[t]*64);
    pt.nt[t] = kNT[t];
  }
  dim3 pgrid(GDIM, NTY);
  k_pool<<<pgrid,64,0,stream>>>(pt, pooled);

  k_final<<<GDIM/4,256,0,stream>>>(pooled, (const float*)d_in[5],
                                   (const float*)d_in[31], (const float*)d_in[32],
                                   (float*)d_out);
}

// Round 13
// 971.729 us; speedup vs baseline: 1.0643x; 1.0643x over previous
//
#include <hip/hip_runtime.h>
#include <math.h>

#define NTY 5
#define NET 10
#define NTOT 307000
#define ETOT 6800000
#define GDIM 1024
#define PDIM 768
#define NGEMMB 7335
#define GSH 2445                      /* gemm share per mega kernel (3 shares) */
#define NBINB 1668                    /* 4096 edges/block */
#define NBK 2949                      /* total buckets */
#define NMEGA_C (NBINB + GSH)
#define NMEGA_B (NBINB + GSH)
#define NMEGA_S (NBK + GSH)
#define NPREPB 802                    /* 2 prep + 640 Wt0 + 160 Wt1 */

using short8 = __attribute__((ext_vector_type(8))) short;
using f32x4  = __attribute__((ext_vector_type(4))) float;

// ---- compile-time problem tables (host) ----
static const int kSRCT[NET]= {0,0,0,4,4,1,2,3,1,2};
static const int kNT[NTY]  = {5000,50000,100000,150000,2000};
static const int kTOFF[NTY]= {0,5000,55000,155000,305000};
static const int kRB[NET+1]= {0,50000,150000,300000,350000,450000,455000,460000,465000,467000,469000};

// ---- device tables ----
__device__ const int gOB[NET]   = {0,50001,150002,300003,350004,450005,455006,460007,465008,467009};
__device__ const int gEB[NET+1] = {0,500000,1500000,2500000,2800000,3400000,3900000,4900000,5900000,6200000,6800000};
__device__ const int gSB[NET]   = {0,5000,10000,15000,17000,19000,69000,169000,319000,369000};
__device__ const int gRB[NET]   = {0,50000,150000,300000,350000,450000,455000,460000,465000,467000};
__device__ const int gND[NET]   = {50000,100000,150000,50000,100000,5000,5000,5000,2000,2000};
__device__ const int gTOFF[NTY] = {0,5000,55000,155000,305000};
__device__ const int gNIN[NTY]  = {3,2,2,1,2};
__device__ const int gINET[NTY][3] = {{5,6,7},{0,3,0},{1,4,0},{2,0,0},{8,9,0}};
__device__ const int gNJ[NET]   = {3,0,0,2,0,2,2,1,0,0};
__device__ const int gTG[NET][3]= {{5,6,7},{0,0,0},{0,0,0},{8,9,0},{0,0,0},{0,3,0},{1,4,0},{2,0,0},{0,0,0},{0,0,0}};
__device__ const int gDSTT[NET] = {1,2,3,1,2,0,0,0,4,4};
// bucket tables: shift per et, bucket base per et
__device__ const int gSH[NET]   = {8,8,8,8,8,4,4,4,4,4};
__device__ const int gBKB[NET+1]= {0,196,587,1173,1369,1760,2073,2386,2699,2824,2949};
// bin blocks per et (4096 edges each), cumulative
__device__ const int gBC[NET+1] = {0,123,368,613,687,834,957,1202,1447,1521,1668};

__device__ __forceinline__ unsigned short f2bf(float f){
  unsigned int u = __float_as_uint(f);
  u += 0x7fffu + ((u>>16)&1u);
  return (unsigned short)(u>>16);
}
__device__ __forceinline__ float bf2f(unsigned short h){
  return __uint_as_float(((unsigned int)h)<<16);
}

struct PrepTab {
  const float* Wd0; const float* ad0; const float* b0;
  const float* Wd1; const float* ad1; const float* b1;
  const float* Ws0; const float* Ws1;
  float* wv0; float* wv1; float* bs0; float* bs1;
  unsigned short* Wt0; unsigned short* Wt1;
};
struct PoolTab { const int* batch[NTY]; const float* x[NTY]; int nt[NTY]; };
struct GemmArgs {
  const float* X[NET];
  const unsigned short* Wt;      // [et][col(64)][K] bf16
  const float* asrc;
  const float* wv;
  unsigned short* hs;            // bf16
  float* ssrc;
  float* sdst;
  int K;
};
struct MCTab {
  GemmArgs g;
  const int* ei[NET];
  int* cntB;
};
struct MBTab {
  GemmArgs g;
  const int* ei[NET];
  int* gcur;
  int2* pairs;
};
struct MSTab {
  GemmArgs g;
  const int2* pairs;
  const int* cntB;
  const int* segB;
  const int* exB;
  int* offs;
  int* csr;
};
struct AggTab {
  const int* offs;
  const int* csr;
  const unsigned short* hs;      // bf16
  const float* ssrc;
  const float* sdst;
  const float* bsum;
  float* xout;
};

// ---------------- weight prep + W transposes ----------------
__global__ __launch_bounds__(256) void k_prep(PrepTab p) {
  int b = blockIdx.x;
  int tid = threadIdx.x;
  if (b == 0) {
    for (int e2=0; e2<NET; e2++){
      const float* W = p.Wd0 + (long)e2*256*64;
      const float* a = p.ad0 + e2*64;
      float s=0.f;
      #pragma unroll 8
      for (int c=0;c<64;c++) s += W[tid*64+c]*a[c];
      p.wv0[e2*256+tid]=s;
    }
    for (int idx=tid; idx<320; idx+=256){
      int ty=idx>>6, c=idx&63; float s=0.f;
      #pragma unroll
      for (int i=0;i<NET;i++) if (gDSTT[i]==ty) s += p.b0[i*64+c];
      p.bs0[idx]=s;
    }
    return;
  }
  if (b == 1) {
    if (tid < 64){
      for (int e2=0; e2<NET; e2++){
        const float* W = p.Wd1 + (long)e2*64*64;
        const float* a = p.ad1 + e2*64;
        float s=0.f;
        #pragma unroll 8
        for (int c=0;c<64;c++) s += W[tid*64+c]*a[c];
        p.wv1[e2*256+tid]=s;
      }
    }
    for (int idx=tid; idx<320; idx+=256){
      int ty=idx>>6, c=idx&63; float s=0.f;
      #pragma unroll
      for (int i=0;i<NET;i++) if (gDSTT[i]==ty) s += p.b1[i*64+c];
      p.bs1[idx]=s;
    }
    return;
  }
  if (b < 2+640) {            // layer0 W transpose: Wt0[et][col][256]
    int i = b-2;
    int et = i>>6, chunk = i&63;
    int idx = chunk*256 + tid;          // col*256 + k
    int col = idx>>8, k = idx&255;
    p.Wt0[(long)et*16384 + idx] = f2bf(p.Ws0[(long)et*16384 + k*64 + col]);
    return;
  }
  {                           // layer1 W transpose: Wt1[et][col][64]
    int i = b-642;
    int et = i>>4, chunk = i&15;
    int idx = chunk*256 + tid;          // col*64 + k
    int col = idx>>6, k = idx&63;
    p.Wt1[(long)et*4096 + idx] = f2bf(p.Ws1[(long)et*4096 + k*64 + col]);
  }
}

// ---------------- bucket scan: exact csr bases + padded pair segments ----------------
__global__ __launch_bounds__(256) void k_scanB(const int* __restrict__ cntB,
                                               int* __restrict__ segB,
                                               int* __restrict__ gcurB,
                                               int* __restrict__ exB) {
  __shared__ int tp[256], te[256];
  int tid = threadIdx.x;
  int base = tid*12;
  int locP[12], locE[12];
  int sp=0, se=0;
  #pragma unroll
  for (int i=0;i<12;i++){
    int b = base+i;
    int v = (b<NBK) ? cntB[b] : 0;
    locE[i]=se; se += v;
    locP[i]=sp; sp += (v+7)&~7;
  }
  tp[tid]=sp; te[tid]=se; __syncthreads();
  for (int off=1; off<256; off<<=1){
    int xp = (tid>=off)? tp[tid-off] : 0;
    int xe = (tid>=off)? te[tid-off] : 0;
    __syncthreads();
    tp[tid]+=xp; te[tid]+=xe;
    __syncthreads();
  }
  int preP = tp[tid]-sp, preE = te[tid]-se;
  #pragma unroll
  for (int i=0;i<12;i++){
    int b = base+i;
    if (b<NBK){
      int v = preP + locP[i];
      segB[b]=v; gcurB[b]=v;
      exB[b]=preE + locE[i];
    }
  }
}

// ---------------- MFMA gemm body (LDS-staged, round-11 version) ----------------
__device__ __forceinline__ void gemm_block(const GemmArgs& t, int b) {
  __shared__ unsigned short sX[64][72];
  __shared__ unsigned short sWt[64][72];
  __shared__ float sdd[3][64][4];
  const int GB1=79,GB2=158,GB3=237,GB4=269,GB5=301,GB6=1083,GB7=2646,GB8=4990,GB9=5772;
  int et = (b>=GB1)+(b>=GB2)+(b>=GB3)+(b>=GB4)+(b>=GB5)+(b>=GB6)+(b>=GB7)+(b>=GB8)+(b>=GB9);
  const int GBb[NET] = {0,GB1,GB2,GB3,GB4,GB5,GB6,GB7,GB8,GB9};
  const int NSa[NET] = {5000,5000,5000,2000,2000,50000,100000,150000,50000,100000};
  int lb = b - GBb[et];
  int Ns = NSa[et];
  int K = t.K;
  const float* X = t.X[et];
  const unsigned short* Wt = t.Wt + (long)et*64*K;
  const float* avec = t.asrc + et*64;
  int sbase = gSB[et];
  unsigned short* HS = t.hs + (long)sbase*64;
  float* score = t.ssrc + sbase;

  int nj = gNJ[et];
  const float* wvA = t.wv + gTG[et][0]*256;
  const float* wvB = t.wv + gTG[et][1]*256;
  const float* wvC = t.wv + gTG[et][2]*256;

  int tid = threadIdx.x;
  int w = tid>>6, lane = tid&63;
  int row0 = lb*64;
  int l15 = lane&15, lg = lane>>4;
  int arow = w*16 + l15;
  int kgrp = lg*8;
  int drow = tid>>2, dq = tid&3;
  f32x4 acc0={0.f,0.f,0.f,0.f}, acc1={0.f,0.f,0.f,0.f}, acc2={0.f,0.f,0.f,0.f}, acc3={0.f,0.f,0.f,0.f};
  float asd0=0.f, asd1=0.f, asd2=0.f;

  for (int k0=0;k0<K;k0+=64){
    #pragma unroll
    for (int p=0;p<4;p++){
      int r = (tid>>4) + 16*p;
      int c = (tid&15)*4;
      int gr = row0 + r;
      float4 xv = make_float4(0.f,0.f,0.f,0.f);
      if (gr < Ns) xv = *(const float4*)(X + (long)gr*K + k0 + c);
      ushort4 o; o.x=f2bf(xv.x); o.y=f2bf(xv.y); o.z=f2bf(xv.z); o.w=f2bf(xv.w);
      *(ushort4*)&sX[r][c] = o;
    }
    {
      int cq = tid>>2, kq = tid&3;
      const unsigned short* ws = Wt + (long)cq*K + k0;
      #pragma unroll
      for (int it=0; it<4; it++){
        int k = kq*4 + it*16;
        *(ushort4*)&sWt[cq][k] = *(const ushort4*)(ws + k);
      }
    }
    __syncthreads();
    #pragma unroll
    for (int ks=0; ks<64; ks+=32){
      short8 af = *(const short8*)&sX[arow][ks+kgrp];
      short8 b0 = *(const short8*)&sWt[ 0+l15][ks+kgrp];
      short8 b1 = *(const short8*)&sWt[16+l15][ks+kgrp];
      short8 b2 = *(const short8*)&sWt[32+l15][ks+kgrp];
      short8 b3 = *(const short8*)&sWt[48+l15][ks+kgrp];
      acc0 = __builtin_amdgcn_mfma_f32_16x16x32_bf16(af, b0, acc0, 0, 0, 0);
      acc1 = __builtin_amdgcn_mfma_f32_16x16x32_bf16(af, b1, acc1, 0, 0, 0);
      acc2 = __builtin_amdgcn_mfma_f32_16x16x32_bf16(af, b2, acc2, 0, 0, 0);
      acc3 = __builtin_amdgcn_mfma_f32_16x16x32_bf16(af, b3, acc3, 0, 0, 0);
    }
    if (nj) {
      int kb = dq*16;
      #pragma unroll
      for (int kk=0; kk<16; kk++){
        float xv = bf2f(sX[drow][kb+kk]);
        asd0 += xv * wvA[k0+kb+kk];
        asd1 += xv * wvB[k0+kb+kk];
        asd2 += xv * wvC[k0+kb+kk];
      }
    }
    __syncthreads();
  }
  if (nj) {
    sdd[0][drow][dq]=asd0;
    sdd[1][drow][dq]=asd1;
    sdd[2][drow][dq]=asd2;
    __syncthreads();
    if (tid < 64) {
      int r = row0 + tid;
      if (r < Ns) {
        for (int j=0;j<nj;j++) {
          float s = sdd[j][tid][0]+sdd[j][tid][1]+sdd[j][tid][2]+sdd[j][tid][3];
          t.sdst[gRB[gTG[et][j]] + r] = s;
        }
      }
    }
  }
  float av0 = avec[ 0+l15], av1 = avec[16+l15], av2 = avec[32+l15], av3 = avec[48+l15];
  int growb = row0 + w*16 + lg*4;
  #pragma unroll
  for (int r=0;r<4;r++){
    int grow = growb + r;
    if (grow < Ns){
      HS[(long)grow*64 +  0+l15] = f2bf(acc0[r]);
      HS[(long)grow*64 + 16+l15] = f2bf(acc1[r]);
      HS[(long)grow*64 + 32+l15] = f2bf(acc2[r]);
      HS[(long)grow*64 + 48+l15] = f2bf(acc3[r]);
    }
    float s = acc0[r]*av0 + acc1[r]*av1 + acc2[r]*av2 + acc3[r]*av3;
    s += __shfl_xor(s, 1);
    s += __shfl_xor(s, 2);
    s += __shfl_xor(s, 4);
    s += __shfl_xor(s, 8);
    if (l15==0 && grow<Ns) score[grow]=s;
  }
}

__global__ __launch_bounds__(256) void k_gemm_all(GemmArgs t) {
  gemm_block(t, blockIdx.x);
}

// ---------------- megaCount: LDS bucket histogram + gemm0[0:GSH] ----------------
__global__ __launch_bounds__(256) void k_megaCount(MCTab t) {
  __shared__ int cnt[640];
  long long b = blockIdx.x;
  const long long G = GSH, T = NMEGA_C;
  long long lo = (b*G)/T, hi = ((b+1)*G)/T;
  if (hi > lo) {
    gemm_block(t.g, (int)lo);
    return;
  }
  int sidx = (int)(b - lo);          // 0..NBINB-1
  int et=0;
  #pragma unroll
  for (int i=0;i<NET;i++) if (sidx >= gBC[i+1]) et=i+1;
  int lb = sidx - gBC[et];
  int E = gEB[et+1]-gEB[et];
  int e0 = lb*4096;
  int eend = e0+4096; if (eend > E) eend = E;
  int sh = gSH[et];
  int nbk = gBKB[et+1]-gBKB[et];
  const int* D = t.ei[et] + E;
  int tid = threadIdx.x;
  for (int j=tid; j<nbk; j+=256) cnt[j]=0;
  __syncthreads();
  #pragma unroll
  for (int i=0;i<16;i++){
    int idx = e0 + i*256 + tid;
    if (idx < eend) atomicAdd(&cnt[D[idx]>>sh], 1);
  }
  __syncthreads();
  int* cb = t.cntB + gBKB[et];
  for (int j=tid; j<nbk; j+=256) if (cnt[j]) atomicAdd(&cb[j], cnt[j]);
}

// ---------------- megaBin: bin pairs into bucket segments + gemm0[GSH:2*GSH] ----------------
__global__ __launch_bounds__(256) void k_megaBin(MBTab t) {
  __shared__ int cnt[640], cnt2[640], gb2[640];
  long long b = blockIdx.x;
  const long long G = GSH, T = NMEGA_B;
  long long lo = (b*G)/T, hi = ((b+1)*G)/T;
  if (hi > lo) {
    gemm_block(t.g, GSH + (int)lo);
    return;
  }
  int sidx = (int)(b - lo);          // 0..NBINB-1
  int et=0;
  #pragma unroll
  for (int i=0;i<NET;i++) if (sidx >= gBC[i+1]) et=i+1;
  int lb = sidx - gBC[et];
  int E = gEB[et+1]-gEB[et];
  int e0 = lb*4096;
  int eend = e0+4096; if (eend > E) eend = E;
  int sh = gSH[et];
  int nbk = gBKB[et+1]-gBKB[et];
  int bkb = gBKB[et];
  const int* EI = t.ei[et];
  int tid = threadIdx.x;
  int sr[16], dv[16];
  #pragma unroll
  for (int i=0;i<16;i++){
    int idx = e0 + i*256 + tid;
    if (idx < eend){ sr[i]=EI[idx]; dv[i]=EI[E+idx]; } else dv[i] = -1;
  }
  for (int j=tid; j<nbk; j+=256){ cnt[j]=0; cnt2[j]=0; }
  __syncthreads();
  #pragma unroll
  for (int i=0;i<16;i++) if (dv[i]>=0) atomicAdd(&cnt[dv[i]>>sh], 1);
  __syncthreads();
  for (int j=tid; j<nbk; j+=256) if (cnt[j]) gb2[j] = atomicAdd(&t.gcur[bkb+j], cnt[j]);
  __syncthreads();
  #pragma unroll
  for (int i=0;i<16;i++) if (dv[i]>=0){
    int bb = dv[i]>>sh;
    int p = gb2[bb] + atomicAdd(&cnt2[bb], 1);
    t.pairs[p] = make_int2(sr[i], dv[i]);
  }
}

// ---------------- megaScat: bucket-local LDS-exact scatter + offs + gemm0[2*GSH:] ----------------
__global__ __launch_bounds__(256) void k_megaScat(MSTab t) {
  __shared__ int cnt[256], sd[256], lcur[256];
  long long b = blockIdx.x;
  const long long G = GSH, T = NMEGA_S;
  long long lo = (b*G)/T, hi = ((b+1)*G)/T;
  if (hi > lo) {
    gemm_block(t.g, 2*GSH + (int)lo);
    return;
  }
  int b2 = (int)(b - lo);            // bucket id 0..NBK-1
  int et=0;
  #pragma unroll
  for (int i=0;i<NET;i++) if (b2 >= gBKB[i+1]) et=i+1;
  int lb = b2 - gBKB[et];
  int sh = gSH[et];
  int nd = gND[et];
  int d0 = lb<<sh;
  int ndst = (1<<sh); if (d0+ndst > nd) ndst = nd-d0;
  int n = t.cntB[b2];
  const int2* pr = t.pairs + t.segB[b2];
  int csrBase = t.exB[b2] - gEB[et];
  int tid = threadIdx.x;
  cnt[tid]=0;
  __syncthreads();
  for (int i=tid; i<n; i+=256) atomicAdd(&cnt[pr[i].y - d0], 1);
  __syncthreads();
  int v = (tid<ndst)? cnt[tid] : 0;
  sd[tid]=v; __syncthreads();
  for (int off=1; off<256; off<<=1){
    int x = (tid>=off)? sd[tid-off] : 0;
    __syncthreads();
    sd[tid]+=x;
    __syncthreads();
  }
  int excl = sd[tid]-v;
  lcur[tid] = excl;
  if (tid < ndst) t.offs[gOB[et] + d0 + tid] = csrBase + excl;
  if (tid==0 && b2 == gBKB[et+1]-1) t.offs[gOB[et] + nd] = gEB[et+1]-gEB[et];
  __syncthreads();
  int* csrb = t.csr + gEB[et] + csrBase;
  for (int i=tid; i<n; i+=256){
    int2 p = pr[i];
    int pos = atomicAdd(&lcur[p.y - d0], 1);
    csrb[pos] = p.x;
  }
}

// ---------------- fused aggregation: 2 edges per wave-step, dword gathers ----------------
__global__ __launch_bounds__(256) void k_agg_all(AggTab t) {
  int nb = blockIdx.x;
  int node0;
  if (nb < 1250)      node0 = nb*4;                       // tag (heavy) first
  else if (nb < 1750) node0 = 305000 + (nb-1250)*4;       // module (heavy)
  else                node0 = 5000 + (nb-1750)*4;         // q/a/c (light)
  int node = node0 + (threadIdx.x>>6);
  int lane = threadIdx.x & 63;
  int l31 = lane & 31;
  bool half = lane >= 32;
  int ty = (node>=5000)+(node>=55000)+(node>=155000)+(node>=305000);
  int r = node - gTOFF[ty];
  float out_lo = 0.f, out_hi = 0.f;
  int ne = gNIN[ty];
  for (int ii=0; ii<ne; ii++) {
    int et = gINET[ty][ii];
    float sd = t.sdst[gRB[et] + r];
    int ob = gOB[et];
    int beg = t.offs[ob + r];
    int end = t.offs[ob + r + 1];
    if (beg >= end) continue;
    const int* cs = t.csr + gEB[et];
    const float* ss = t.ssrc + gSB[et];
    const unsigned int* hsw = (const unsigned int*)(t.hs + (long)gSB[et]*64);
    float denl = 0.f, acc_lo = 0.f, acc_hi = 0.f;
    for (int chunk = beg; chunk < end; chunk += 64) {
      int n = end - chunk; if (n > 64) n = 64;
      int s = 0; float ex = 0.f;
      if (lane < n) {
        s = cs[chunk + lane];
        float l = ss[s] + sd;
        l = (l>0.f)? l : 0.2f*l;
        ex = __expf(l);
      }
      denl += ex;
      unsigned int exu = __float_as_uint(ex);
      // pairs: lanes 0-31 take edge j, lanes 32-63 take edge j+1.
      // padding lanes have s=0, ex=0 -> contribute nothing, addresses valid.
      for (int j = 0; j < n; j += 8) {
        #pragma unroll
        for (int q = 0; q < 4; q++) {
          int a0 = __builtin_amdgcn_readlane(s, j+2*q);
          int a1 = __builtin_amdgcn_readlane(s, j+2*q+1);
          float e0 = __uint_as_float(__builtin_amdgcn_readlane(exu, j+2*q));
          float e1 = __uint_as_float(__builtin_amdgcn_readlane(exu, j+2*q+1));
          int   ssel = half ? a1 : a0;
          float esel = half ? e1 : e0;
          unsigned int u = hsw[(long)ssel*32 + l31];
          acc_lo += esel * __uint_as_float(u << 16);
          acc_hi += esel * __uint_as_float(u & 0xffff0000u);
        }
      }
    }
    #pragma unroll
    for (int off=32; off; off>>=1) denl += __shfl_xor(denl, off);
    acc_lo += __shfl_xor(acc_lo, 32);
    acc_hi += __shfl_xor(acc_hi, 32);
    float inv = 1.f/(denl+1e-16f);
    out_lo += acc_lo*inv;
    out_hi += acc_hi*inv;
  }
  if (!half) {
    float b0 = t.bsum[ty*64 + 2*l31];
    float b1 = t.bsum[ty*64 + 2*l31 + 1];
    float2 o;
    o.x = fmaxf(out_lo + b0, 0.f);
    o.y = fmaxf(out_hi + b1, 0.f);
    *(float2*)(t.xout + (long)node*64 + 2*l31) = o;
  }
}

// ---------------- pooling + head ----------------
__global__ __launch_bounds__(64) void k_pool(PoolTab t, float* __restrict__ pooled) {
  int g = blockIdx.x; int ty = blockIdx.y; int lane = threadIdx.x;
  const int* batch = t.batch[ty];
  int n = t.nt[ty];
  int lo=0, hi=0;
  if (lane==0){
    int a=0,b2=n;
    while(a<b2){int mm=(a+b2)>>1; if (batch[mm]<g) a=mm+1; else b2=mm;}
    lo=a;
    a=lo; b2=n;
    while(a<b2){int mm=(a+b2)>>1; if (batch[mm]<g+1) a=mm+1; else b2=mm;}
    hi=a;
  }
  lo=__shfl(lo,0); hi=__shfl(hi,0);
  const float* x = t.x[ty];
  float acc=0.f;
  for (int i=lo;i<hi;i++) acc += x[(long)i*64+lane];
  int cnt = hi-lo;
  pooled[(long)g*320 + ty*64 + lane] = acc / (float)(cnt>0?cnt:1);
}

__global__ __launch_bounds__(256) void k_final(
    const float* __restrict__ pooled, const float* __restrict__ post,
    const float* __restrict__ Wlin, const float* __restrict__ blin,
    float* __restrict__ out)
{
  int w = (blockIdx.x*256+threadIdx.x)>>6;
  int lane = threadIdx.x&63;
  if (w>=GDIM) return;
  float a0=0.f,a1=0.f;
  for (int k=lane;k<320+PDIM;k+=64){
    float v = (k<320) ? pooled[(long)w*320+k] : post[(long)w*PDIM + (k-320)];
    a0 += v*Wlin[k*2];
    a1 += v*Wlin[k*2+1];
  }
  #pragma unroll
  for (int off=32;off;off>>=1){ a0+=__shfl_xor(a0,off); a1+=__shfl_xor(a1,off); }
  if (lane==0){
    float z0=a0+blin[0], z1=a1+blin[1];
    z0=fmaxf(z0,0.f); z1=fmaxf(z1,0.f);
    float mm=fmaxf(z0,z1);
    float e0=__expf(z0-mm), e1=__expf(z1-mm);
    float inv = 1.f/(e0+e1);
    out[w*2+0]=e0*inv; out[w*2+1]=e1*inv;
  }
}

extern "C" void kernel_launch(void* const* d_in, const int* in_sizes, int n_in,
                              void* d_out, int out_size, void* d_ws, size_t ws_size,
                              hipStream_t stream) {
  (void)in_sizes; (void)n_in; (void)out_size; (void)ws_size;
  char* ws = (char*)d_ws;
  size_t off = 0;
  auto A = [&](size_t nbytes){ size_t o=off; off=(off+nbytes+255)&~((size_t)255); return o; };
  size_t xbuf1_o = A((size_t)NTOT*64*4);
  size_t xbuf2_o = A((size_t)NTOT*64*4);
  size_t hs_o    = A((size_t)469000*64*2);
  size_t csr_o   = A((size_t)ETOT*4);
  size_t pairs_o = A((size_t)6832000*8);
  size_t offs_o  = A((size_t)469010*4);
  size_t ssrc_o  = A((size_t)469000*4);
  size_t sdst_o  = A((size_t)469000*4);
  size_t pool_o  = A((size_t)GDIM*320*4);
  size_t wv0_o   = A((size_t)NET*256*4);
  size_t wv1_o   = A((size_t)NET*256*4);
  size_t bs0_o   = A((size_t)320*4);
  size_t bs1_o   = A((size_t)320*4);
  size_t cntB_o  = A((size_t)NBK*4);
  size_t segB_o  = A((size_t)NBK*4);
  size_t gcurB_o = A((size_t)NBK*4);
  size_t exB_o   = A((size_t)NBK*4);
  size_t wt0_o   = A((size_t)NET*64*256*2);
  size_t wt1_o   = A((size_t)NET*64*64*2);

  float* xbuf1 = (float*)(ws + xbuf1_o);
  float* xbuf2 = (float*)(ws + xbuf2_o);
  unsigned short* hsB = (unsigned short*)(ws + hs_o);
  int*   csr   = (int*)(ws + csr_o);
  int2*  pairs = (int2*)(ws + pairs_o);
  int*   offs  = (int*)(ws + offs_o);
  float* ssrcB = (float*)(ws + ssrc_o);
  float* sdstA = (float*)(ws + sdst_o);
  float* pooled= (float*)(ws + pool_o);
  float* wv0   = (float*)(ws + wv0_o);
  float* wv1   = (float*)(ws + wv1_o);
  float* bs0   = (float*)(ws + bs0_o);
  float* bs1   = (float*)(ws + bs1_o);
  int*   cntB  = (int*)(ws + cntB_o);
  int*   segB  = (int*)(ws + segB_o);
  int*   gcurB = (int*)(ws + gcurB_o);
  int*   exB   = (int*)(ws + exB_o);
  unsigned short* Wt0 = (unsigned short*)(ws + wt0_o);
  unsigned short* Wt1 = (unsigned short*)(ws + wt1_o);

  PrepTab pp;
  pp.Wd0 = (const float*)d_in[22]; pp.ad0 = (const float*)d_in[24]; pp.b0 = (const float*)d_in[25];
  pp.Wd1 = (const float*)d_in[27]; pp.ad1 = (const float*)d_in[29]; pp.b1 = (const float*)d_in[30];
  pp.Ws0 = (const float*)d_in[21]; pp.Ws1 = (const float*)d_in[26];
  pp.wv0 = wv0; pp.wv1 = wv1; pp.bs0 = bs0; pp.bs1 = bs1;
  pp.Wt0 = Wt0; pp.Wt1 = Wt1;

  hipMemsetAsync(cntB, 0, (size_t)NBK*4, stream);
  k_prep<<<NPREPB,256,0,stream>>>(pp);

  // ---- megaCount: bucket histogram + first share of layer-0 gemm ----
  MCTab mc;
  for (int e=0;e<NET;e++) mc.g.X[e] = (const float*)d_in[kSRCT[e]];
  mc.g.Wt = Wt0;
  mc.g.asrc = (const float*)d_in[23];
  mc.g.wv = wv0; mc.g.hs = hsB; mc.g.ssrc = ssrcB; mc.g.sdst = sdstA; mc.g.K = 256;
  for (int i=0;i<NET;i++) mc.ei[i] = (const int*)d_in[6+i];
  mc.cntB = cntB;
  k_megaCount<<<NMEGA_C,256,0,stream>>>(mc);

  k_scanB<<<1,256,0,stream>>>(cntB, segB, gcurB, exB);

  // ---- megaBin: pair binning + second share of gemm0 ----
  MBTab mb;
  mb.g = mc.g;
  for (int i=0;i<NET;i++) mb.ei[i] = (const int*)d_in[6+i];
  mb.gcur = gcurB; mb.pairs = pairs;
  k_megaBin<<<NMEGA_B,256,0,stream>>>(mb);

  // ---- megaScat: bucket-local scatter + offs + last share of gemm0 ----
  MSTab ms;
  ms.g = mc.g;
  ms.pairs = pairs; ms.cntB = cntB; ms.segB = segB; ms.exB = exB;
  ms.offs = offs; ms.csr = csr;
  k_megaScat<<<NMEGA_S,256,0,stream>>>(ms);

  // ---- layer-0 agg ----
  AggTab a0;
  a0.offs = offs; a0.csr = csr; a0.hs = hsB; a0.ssrc = ssrcB;
  a0.sdst = sdstA; a0.bsum = bs0; a0.xout = xbuf1;
  k_agg_all<<<NTOT/4,256,0,stream>>>(a0);

  // ---- layer-1 gemm ----
  GemmArgs g1;
  for (int e=0;e<NET;e++) g1.X[e] = (const float*)(xbuf1 + (long)kTOFF[kSRCT[e]]*64);
  g1.Wt = Wt1;
  g1.asrc = (const float*)d_in[28];
  g1.wv = wv1; g1.hs = hsB; g1.ssrc = ssrcB; g1.sdst = sdstA; g1.K = 64;
  k_gemm_all<<<NGEMMB,256,0,stream>>>(g1);

  // ---- layer-1 agg ----
  AggTab a1;
  a1.offs = offs; a1.csr = csr; a1.hs = hsB; a1.ssrc = ssrcB;
  a1.sdst = sdstA; a1.bsum = bs1; a1.xout = xbuf2;
  k_agg_all<<<NTOT/4,256,0,stream>>>(a1);

  // ---- pooling + head ----
  PoolTab pt;
  for (int t=0;t<NTY;t++){
    pt.batch[t] = (const int*)d_in[16+t];
    pt.x[t] = (const float*)(xbuf2 + (long)kTOFF[t]*64);
    pt.nt[t] = kNT[t];
  }
  dim3 pgrid(GDIM, NTY);
  k_pool<<<pgrid,64,0,stream>>>(pt, pooled);

  k_final<<<GDIM/4,256,0,stream>>>(pooled, (const float*)d_in[5],
                                   (const float*)d_in[31], (const float*)d_in[32],
                                   (float*)d_out);
}